// Round 12
// baseline (1421.220 us; speedup 1.0000x reference)
//
#include <hip/hip_runtime.h>

#define DEV __device__ __forceinline__

DEV float fast_rcp(float x) {
#if __has_builtin(__builtin_amdgcn_rcpf)
  return __builtin_amdgcn_rcpf(x);
#else
  return 1.0f / x;
#endif
}
DEV float sigm(float x) { return fast_rcp(1.0f + __expf(-x)); }
DEV float tanh_f(float x) {
  float e = __expf(-2.0f * fabsf(x));
  float t = 1.0f - 2.0f * e * fast_rcp(1.0f + e);
  return copysignf(t, x);
}
DEV float lrelu(float x) { return x > 0.0f ? x : 0.01f * x; }

DEV float wave_sum(float v) {
#pragma unroll
  for (int m = 32; m; m >>= 1) v += __shfl_xor(v, m);
  return v;
}
DEV float wave_max(float v) {
#pragma unroll
  for (int m = 32; m; m >>= 1) v = fmaxf(v, __shfl_xor(v, m));
  return v;
}
DEV float dot4(float4 w, float4 x, float acc) {
  acc = fmaf(w.x, x.x, acc);
  acc = fmaf(w.y, x.y, acc);
  acc = fmaf(w.z, x.z, acc);
  acc = fmaf(w.w, x.w, acc);
  return acc;
}

// SGPR broadcast of another lane's register value — VALU pipe, NOT DS pipe.
DEV float bcast(float v, int lane) {
  return __int_as_float(__builtin_amdgcn_readlane(__float_as_int(v), lane));
}

// ---------------------------------------------------------------------------
// Persistent-GRU encoder, R14. Counter-resolved model after R11-R13 plateau
// (1086/1115/1127us):
//  * Broadcast LDS reads deliver unique data at only ~2 B/cyc (64-lane
//    return-path replication; conflict counter logs the extra phases:
//    uniform b128 h-reads explain R7==R8==2.043e8 and R13's 9.18e7).
//    -> LDS-h variants (R12/R13) floor at ~16k cyc/CU-step for h alone.
//  * R10/R11 (readlane h): VALUBusy 36k cyc/SIMD-step vs ~9k hand-counted
//    issues -> ~8 cyc VALU->SGPR->VALU hazard wait-state per readlane
//    (result consumed ~1 instr after production).
// R14 = R10 structure (register h + readlane, b32 stride-3 weights with
// measured-ZERO conflicts) + HAZARD-DISTANCE BATCHING: each dot phase is
// processed in groups of 8 k-rows — all 24 weight loads + 40 readlanes
// issued first, then 120 FMAs. First consumer ~40 instrs after its
// readlane -> hazard slots filled with independent work.
// Rules kept: outer kb loops ROLLED (RULE 1); no min-waves launch-bounds
// (RULE 3). Partition: 256 blocks x 8 waves x SPW=5 = ONE balanced round.
// LDS = weights only (147,456 B). h/x state in registers.
// ---------------------------------------------------------------------------
constexpr int E_SPW = 5;
constexpr int E_WAVES = 8;
constexpr int L_W0 = 0;          // Whh0 rows (w3e0 rows 6..69): 64*192 dw
constexpr int L_W1 = 12288;      // w3e1: 128*192 dw
constexpr int E_DW = 36864;
constexpr int E_LDS = E_DW * 4;  // 147,456 B <= 160 KiB

// One batch of 8 k-rows: load 24 weights (b32, conflict-free) + 40
// readlanes FIRST, then 120 FMAs. Accumulators ar/az fixed names; n-gate
// target passed (anh or anx).
#define DOT_BATCH8(WBASE, KB, HREG, AN)                                   \
  {                                                                       \
    float wv_[8][3];                                                      \
    float hh_[8][E_SPW];                                                  \
    _Pragma("unroll") for (int u = 0; u < 8; ++u) {                       \
      const int k_ = (KB) * 8 + u;                                        \
      const int wb_ = (WBASE) + k_ * 192 + j3;                            \
      wv_[u][0] = lds[wb_];                                               \
      wv_[u][1] = lds[wb_ + 1];                                           \
      wv_[u][2] = lds[wb_ + 2];                                           \
      _Pragma("unroll") for (int s = 0; s < E_SPW; ++s)                   \
        hh_[u][s] = bcast(HREG[s], k_);                                   \
    }                                                                     \
    _Pragma("unroll") for (int u = 0; u < 8; ++u) {                       \
      _Pragma("unroll") for (int s = 0; s < E_SPW; ++s) {                 \
        ar[s] = fmaf(wv_[u][0], hh_[u][s], ar[s]);                        \
        az[s] = fmaf(wv_[u][1], hh_[u][s], az[s]);                        \
        AN[s] = fmaf(wv_[u][2], hh_[u][s], AN[s]);                        \
      }                                                                   \
    }                                                                     \
  }

__launch_bounds__(512)
__global__ void gru2_enc(const float* __restrict__ x,      // [10240][60][6]
                         const float* __restrict__ w3e0,   // [70][192] j3-interleave
                         const float* __restrict__ w3e1,   // [128][192]
                         const float* __restrict__ bih0, const float* __restrict__ bhh0,
                         const float* __restrict__ bih1, const float* __restrict__ bhh1,
                         float* __restrict__ h_out) {      // [10240][64]
  extern __shared__ float lds[];
  const int tid = threadIdx.x;
  const int wave = tid >> 6;
  const int j = tid & 63;
  const int j3 = j * 3;

  // cooperative weight load into LDS (coalesced float4)
  {
    const float4* s0 = (const float4*)(w3e0 + 6 * 192);  // Whh0 rows
    for (int i = tid; i < 12288 / 4; i += 512) ((float4*)(lds + L_W0))[i] = s0[i];
    const float4* s1 = (const float4*)w3e1;
    for (int i = tid; i < 24576 / 4; i += 512) ((float4*)(lds + L_W1))[i] = s1[i];
  }
  // register weights: Wih0 (6 rows x 3 gates per lane)
  float wx0[6][3];
#pragma unroll
  for (int k = 0; k < 6; ++k)
#pragma unroll
    for (int g = 0; g < 3; ++g) wx0[k][g] = w3e0[k * 192 + j3 + g];

  const float br0 = bih0[j] + bhh0[j];
  const float bz0 = bih0[64 + j] + bhh0[64 + j];
  const float bxn0 = bih0[128 + j];
  const float bhn0 = bhh0[128 + j];
  const float br1 = bih1[j] + bhh1[j];
  const float bz1 = bih1[64 + j] + bhh1[64 + j];
  const float bxn1 = bih1[128 + j];
  const float bhn1 = bhh1[128 + j];

  float h0r[E_SPW], h1r[E_SPW];
#pragma unroll
  for (int s = 0; s < E_SPW; ++s) { h0r[s] = 0.0f; h1r[s] = 0.0f; }
  __syncthreads();  // weights visible; the only barrier

  const int seq0 = blockIdx.x * (E_WAVES * E_SPW) + wave * E_SPW;
  // x carrier: lane j<30 holds component ci of seq si; consumed via readlane
  const int si = j / 6;
  const int ci = j - si * 6;
  const bool xlane = (j < 6 * E_SPW);
  const float* xg = x + (size_t)(seq0 + si) * 360 + ci;

  float xcur = xlane ? xg[0] : 0.0f;  // t = 0

  for (int t = 0; t < 60; ++t) {
    float xnext = (xlane && t + 1 < 60) ? xg[(size_t)(t + 1) * 6] : 0.0f;

    float ar[E_SPW], az[E_SPW], anx[E_SPW], anh[E_SPW];
#pragma unroll
    for (int s = 0; s < E_SPW; ++s) { ar[s] = 0.f; az[s] = 0.f; anx[s] = 0.f; anh[s] = 0.f; }

    // ---- layer0 h-part: 8 batches of 8 rows (outer loop ROLLED)
#pragma clang loop unroll(disable)
    for (int kb = 0; kb < 8; ++kb) DOT_BATCH8(L_W0, kb, h0r, anh)

    // ---- layer0 x-part: register weights, x via readlane (batched too)
    {
      float xk_[E_SPW][6];
#pragma unroll
      for (int s = 0; s < E_SPW; ++s)
#pragma unroll
        for (int c = 0; c < 6; ++c) xk_[s][c] = bcast(xcur, s * 6 + c);
#pragma unroll
      for (int s = 0; s < E_SPW; ++s)
#pragma unroll
        for (int c = 0; c < 6; ++c) {
          ar[s] = fmaf(wx0[c][0], xk_[s][c], ar[s]);
          az[s] = fmaf(wx0[c][1], xk_[s][c], az[s]);
          anx[s] = fmaf(wx0[c][2], xk_[s][c], anx[s]);
        }
    }
    // ---- layer0 epilogue: lane j owns all 3 gates of unit j; pure register
#pragma unroll
    for (int s = 0; s < E_SPW; ++s) {
      float r = sigm(ar[s] + br0);
      float z = sigm(az[s] + bz0);
      float n = tanh_f(anx[s] + bxn0 + r * (anh[s] + bhn0));
      h0r[s] = (1.0f - z) * n + z * h0r[s];
    }

#pragma unroll
    for (int s = 0; s < E_SPW; ++s) { ar[s] = 0.f; az[s] = 0.f; anx[s] = 0.f; anh[s] = 0.f; }
    // ---- layer1 x-part over fresh h0 (readlane of new h0r)
#pragma clang loop unroll(disable)
    for (int kb = 0; kb < 8; ++kb) DOT_BATCH8(L_W1, kb, h0r, anx)
    // ---- layer1 h-part over h1_old
#pragma clang loop unroll(disable)
    for (int kb = 0; kb < 8; ++kb) DOT_BATCH8(L_W1 + 64 * 192, kb, h1r, anh)
    // ---- layer1 epilogue
#pragma unroll
    for (int s = 0; s < E_SPW; ++s) {
      float r = sigm(ar[s] + br1);
      float z = sigm(az[s] + bz1);
      float n = tanh_f(anx[s] + bxn1 + r * (anh[s] + bhn1));
      h1r[s] = (1.0f - z) * n + z * h1r[s];
    }
    xcur = xnext;
  }

#pragma unroll
  for (int s = 0; s < E_SPW; ++s)
    h_out[(size_t)(seq0 + s) * 64 + j] = h1r[s];
}

// ---------------------------------------------------------------------------
// Single-layer GRU for the ALSTM (I = 64). Unchanged (validated; small share
// of runtime). 8 waves/block, 1 seq/wave, grid 64.
// ---------------------------------------------------------------------------
constexpr int A_W_DW = 128 * 192;  // 24576
constexpr int A_WAVES = 8;
constexpr int A_LDS = (A_W_DW + A_WAVES * 128) * 4;  // 102400 B

__launch_bounds__(512, 2)
__global__ void gru1(const float* __restrict__ xin,  // [N][T][64]
                     const float* __restrict__ w3,   // [128][192]
                     const float* __restrict__ bih, const float* __restrict__ bhh,
                     int T,
                     float* __restrict__ rout) {     // [N][T][64]
  extern __shared__ float lds[];
  const int tid = threadIdx.x;
  const int wave = tid >> 6;
  const int j = tid & 63;
  const int j3 = j * 3;
  const int XB = A_W_DW + wave * 128;  // [0..63]=x_t, [64..127]=h

  {
    const float4* sp = (const float4*)w3;
    for (int i = tid; i < A_W_DW / 4; i += 512) ((float4*)lds)[i] = sp[i];
  }
  const float br = bih[j] + bhh[j];
  const float bz = bih[64 + j] + bhh[64 + j];
  const float bxn = bih[128 + j];
  const float bhn = bhh[128 + j];

  float hr = 0.0f;
  lds[XB + 64 + j] = 0.0f;
  __syncthreads();

  const int seq = blockIdx.x * A_WAVES + wave;
  const float* xs = xin + (size_t)seq * T * 64;

#define A_QUAD(WROW0, HOFF, AN)                                            \
  {                                                                        \
    float4 hv = *(const float4*)&lds[XB + (HOFF)];                         \
    _Pragma("unroll") for (int c = 0; c < 4; ++c) {                        \
      const float wr = lds[((WROW0) + c) * 192 + j3];                      \
      const float wz = lds[((WROW0) + c) * 192 + j3 + 1];                  \
      const float wn = lds[((WROW0) + c) * 192 + j3 + 2];                  \
      const float hc = (c == 0) ? hv.x : (c == 1) ? hv.y                   \
                      : (c == 2) ? hv.z : hv.w;                            \
      ar = fmaf(wr, hc, ar);                                               \
      az = fmaf(wz, hc, az);                                               \
      AN = fmaf(wn, hc, AN);                                               \
    }                                                                      \
  }

  float xcur = xs[j];  // t = 0
  for (int t = 0; t < T; ++t) {
    float xnext = (t + 1 < T) ? xs[(size_t)(t + 1) * 64 + j] : 0.0f;
    lds[XB + j] = xcur;  // wave-private; ordered by lgkmcnt

    float ar = 0.f, az = 0.f, anx = 0.f, anh = 0.f;
#pragma unroll
    for (int kq = 0; kq < 16; ++kq) A_QUAD(kq * 4, kq * 4, anx);        // input
#pragma unroll
    for (int kq = 0; kq < 16; ++kq) A_QUAD(64 + kq * 4, 64 + kq * 4, anh);  // rec

    float r = sigm(ar + br);
    float z = sigm(az + bz);
    float n = tanh_f(anx + bxn + r * (anh + bhn));
    float h = (1.0f - z) * n + z * hr;
    hr = h;
    lds[XB + 64 + j] = h;
    rout[((size_t)seq * T + t) * 64 + j] = h;
    xcur = xnext;
  }
#undef A_QUAD
}

// ---------------------------------------------------------------------------
// Weight interleave prep (R1 format): W3[k][j*3+g] =
//   (k<I ? Wih[g*64+j][k] : Whh[g*64+j][k-I])
// Sections: 0: e0 [70][192] (I=6); 1: e1 [128][192]; 2,3: ALSTM a0,a1.
// ---------------------------------------------------------------------------
__global__ void w3_prep(const float* __restrict__ Wih0, const float* __restrict__ Whh0,
                        const float* __restrict__ Wih1, const float* __restrict__ Whh1,
                        const float* __restrict__ aWih0, const float* __restrict__ aWhh0,
                        const float* __restrict__ aWih1, const float* __restrict__ aWhh1,
                        float* __restrict__ d_e0, float* __restrict__ d_e1,
                        float* __restrict__ d_a0, float* __restrict__ d_a1) {
  const int sec = blockIdx.x >> 3;
  const int bi = blockIdx.x & 7;
  const float* Wih; const float* Whh; float* dst; int I;
  if (sec == 0)      { Wih = Wih0;  Whh = Whh0;  dst = d_e0; I = 6; }
  else if (sec == 1) { Wih = Wih1;  Whh = Whh1;  dst = d_e1; I = 64; }
  else if (sec == 2) { Wih = aWih0; Whh = aWhh0; dst = d_a0; I = 64; }
  else               { Wih = aWih1; Whh = aWhh1; dst = d_a1; I = 64; }
  const int tot = (I + 64) * 192;
  for (int idx = bi * blockDim.x + threadIdx.x; idx < tot; idx += 8 * blockDim.x) {
    const int k = idx / 192;
    const int rem = idx - k * 192;
    const int jj = rem / 3;
    const int g = rem - jj * 3;
    dst[idx] = (k < I) ? Wih[(g * 64 + jj) * I + k] : Whh[(g * 64 + jj) * 64 + (k - I)];
  }
}

// ---------------------------------------------------------------------------
// GAT algebraic prep
// ---------------------------------------------------------------------------
__global__ void gat_prep(const float* __restrict__ tW, const float* __restrict__ tb,
                         const float* __restrict__ a, float* __restrict__ vbuf) {
  const int d = threadIdx.x;  // 64 threads
  float vd = 0.0f, vs = 0.0f;
  for (int e = 0; e < 64; ++e) {
    float w = tW[e * 64 + d];
    vd = fmaf(w, a[e], vd);
    vs = fmaf(w, a[64 + e], vs);
  }
  vbuf[d] = vd;
  vbuf[64 + d] = vs;
  if (d == 0) {
    float cd = 0.0f, cs = 0.0f;
    for (int e = 0; e < 64; ++e) {
      cd = fmaf(tb[e], a[e], cd);
      cs = fmaf(tb[e], a[64 + e], cs);
    }
    vbuf[128] = cd;
    vbuf[129] = cs;
  }
}

__global__ void gat_svals(const float* __restrict__ h_enc, const float* __restrict__ vbuf,
                          float* __restrict__ s_src, float* __restrict__ s_dst) {
  const int wave = (blockIdx.x * blockDim.x + threadIdx.x) >> 6;
  const int lane = threadIdx.x & 63;
  float h = h_enc[(size_t)wave * 64 + lane];
  float pd = h * vbuf[lane];
  float ps = h * vbuf[64 + lane];
  pd = wave_sum(pd);
  ps = wave_sum(ps);
  if (lane == 0) {
    s_dst[wave] = pd + vbuf[128];
    s_src[wave] = ps + vbuf[129];
  }
}

// ---------------------------------------------------------------------------
// Dense all-pairs attention per group k (m=512)
// ---------------------------------------------------------------------------
__launch_bounds__(256)
__global__ void gat_attn(const float* __restrict__ h_enc,
                         const float* __restrict__ s_src,
                         const float* __restrict__ s_dst,
                         float* __restrict__ hout) {
  const int k = blockIdx.x >> 7;
  const int tile = blockIdx.x & 127;
  const int wv = threadIdx.x >> 6;
  const int lane = threadIdx.x & 63;
  const int i = tile * 4 + wv;
  __shared__ float sdbuf[512];
  __shared__ __align__(16) float pbuf[4][512];

  for (int u = threadIdx.x; u < 512; u += 256) sdbuf[u] = s_dst[k * 512 + u];
  __syncthreads();

  const float si = s_src[k * 512 + i];
  float ev[8];
  float mx = -1e30f;
#pragma unroll
  for (int u = 0; u < 8; ++u) {
    ev[u] = lrelu(si + sdbuf[lane + u * 64]);
    mx = fmaxf(mx, ev[u]);
  }
  mx = wave_max(mx);
  float lsum = 0.0f;
#pragma unroll
  for (int u = 0; u < 8; ++u) {
    float p = __expf(ev[u] - mx);
    pbuf[wv][lane + u * 64] = p;
    lsum += p;
  }
  lsum = wave_sum(lsum);
  const float inv = fast_rcp(lsum);

  const float* hk = h_enc + (size_t)k * 512 * 64;
  const float4* pv = (const float4*)pbuf[wv];
  float acc0 = 0.0f, acc1 = 0.0f;
#pragma unroll 2
  for (int jj = 0; jj < 128; ++jj) {
    float4 p = pv[jj];
    const float* hp = hk + (size_t)(jj * 4) * 64 + lane;
    acc0 = fmaf(p.x, hp[0], acc0);
    acc1 = fmaf(p.y, hp[64], acc1);
    acc0 = fmaf(p.z, hp[128], acc0);
    acc1 = fmaf(p.w, hp[192], acc1);
  }
  hout[((size_t)k * 512 + i) * 64 + lane] =
      (acc0 + acc1) * inv + hk[(size_t)i * 64 + lane];
}

// ---------------------------------------------------------------------------
// Post-GAT transform + pred head + ALSTM input transform
// ---------------------------------------------------------------------------
__launch_bounds__(256)
__global__ void gat_out(const float* __restrict__ hin,
                        const float* __restrict__ fcW, const float* __restrict__ fcb,
                        const float* __restrict__ fcoW, const float* __restrict__ fcob,
                        const float* __restrict__ alinW, const float* __restrict__ alinb,
                        float* __restrict__ zout, float* __restrict__ pred) {
  const int wv = threadIdx.x >> 6;
  const int lane = threadIdx.x & 63;
  const int n = blockIdx.x * 4 + wv;  // [0,10240)
  const int k = n >> 9;
  const int i = n & 511;
  __shared__ __align__(16) float rbuf[4][64];
  __shared__ __align__(16) float rbuf2[4][64];

  float4 fw[16], aw[16];
  {
    const float4* p1 = (const float4*)(fcW + lane * 64);
    const float4* p2 = (const float4*)(alinW + lane * 64);
#pragma unroll
    for (int kk = 0; kk < 16; ++kk) fw[kk] = p1[kk];
#pragma unroll
    for (int kk = 0; kk < 16; ++kk) aw[kk] = p2[kk];
  }

  rbuf[wv][lane] = hin[(size_t)n * 64 + lane];
  float h2 = fcb[lane];
  const float4* rv = (const float4*)rbuf[wv];
#pragma unroll
  for (int kk = 0; kk < 16; ++kk) h2 = dot4(fw[kk], rv[kk], h2);

  if (k == 19) {
    float pv = lrelu(h2) * fcoW[lane];
    pv = wave_sum(pv);
    if (lane == 0) pred[i] = pv + fcob[0];
  }

  rbuf2[wv][lane] = h2;
  float zz = alinb[lane];
  const float4* rv2 = (const float4*)rbuf2[wv];
#pragma unroll
  for (int kk = 0; kk < 16; ++kk) zz = dot4(aw[kk], rv2[kk], zz);
  zout[((size_t)i * 20 + k) * 64 + lane] = tanh_f(zz);
}

// ---------------------------------------------------------------------------
// ALSTM attention head
// ---------------------------------------------------------------------------
__launch_bounds__(256)
__global__ void alstm_head(const float* __restrict__ r1,  // [512][20][64]
                           const float* __restrict__ W1,  // [32][64]
                           const float* __restrict__ b1,  // [32]
                           const float* __restrict__ W2,  // [32]
                           const float* __restrict__ Wo,  // [128]
                           const float* __restrict__ bo,  // [1]
                           float* __restrict__ alstm_out) {
  const int wv = threadIdx.x >> 6;
  const int lane = threadIdx.x & 63;
  const int i = blockIdx.x * 4 + wv;  // [0,512)
  const int e = lane & 31;
  __shared__ __align__(16) float rbuf[4][64];
  __shared__ float scb[4][20];

  float4 w1r[16];
  {
    const float4* p = (const float4*)(W1 + e * 64);
#pragma unroll
    for (int kk = 0; kk < 16; ++kk) w1r[kk] = p[kk];
  }
  const float b1e = b1[e];
  const float w2e = W2[e];

  for (int k = 0; k < 20; ++k) {
    rbuf[wv][lane] = r1[((size_t)i * 20 + k) * 64 + lane];
    float u = b1e;
    const float4* rp = (const float4*)rbuf[wv];
#pragma unroll
    for (int kk = 0; kk < 16; ++kk) u = dot4(w1r[kk], rp[kk], u);
    u = tanh_f(u) * w2e;
#pragma unroll
    for (int m = 16; m; m >>= 1) u += __shfl_xor(u, m);
    if (lane == 0) scb[wv][k] = u;
  }

  float mx = -1e30f;
#pragma unroll
  for (int k = 0; k < 20; ++k) mx = fmaxf(mx, scb[wv][k]);
  float p[20];
  float l = 0.0f;
#pragma unroll
  for (int k = 0; k < 20; ++k) {
    p[k] = __expf(scb[wv][k] - mx);
    l += p[k];
  }
  const float inv = fast_rcp(l);

  float oa = 0.0f, rlast = 0.0f;
#pragma unroll
  for (int k = 0; k < 20; ++k) {
    float rv = r1[((size_t)i * 20 + k) * 64 + lane];
    oa = fmaf(p[k], rv, oa);
    if (k == 19) rlast = rv;
  }
  oa *= inv;
  float v = fmaf(Wo[lane], rlast, Wo[64 + lane] * oa);
  v = wave_sum(v);
  if (lane == 0) alstm_out[i] = v + bo[0];
}

// ---------------------------------------------------------------------------
extern "C" void kernel_launch(void* const* d_in, const int* in_sizes, int n_in,
                              void* d_out, int out_size, void* d_ws, size_t ws_size,
                              hipStream_t stream) {
  const float* x      = (const float*)d_in[0];
  const float* Wih0   = (const float*)d_in[1];
  const float* Whh0   = (const float*)d_in[2];
  const float* bih0   = (const float*)d_in[3];
  const float* bhh0   = (const float*)d_in[4];
  const float* Wih1   = (const float*)d_in[5];
  const float* Whh1   = (const float*)d_in[6];
  const float* bih1   = (const float*)d_in[7];
  const float* bhh1   = (const float*)d_in[8];
  const float* transW = (const float*)d_in[9];
  const float* transb = (const float*)d_in[10];
  const float* a_vec  = (const float*)d_in[11];
  const float* fcW    = (const float*)d_in[12];
  const float* fcb    = (const float*)d_in[13];
  const float* fcoW   = (const float*)d_in[14];
  const float* fcob   = (const float*)d_in[15];
  const float* alinW  = (const float*)d_in[16];
  const float* alinb  = (const float*)d_in[17];
  const float* aWih0  = (const float*)d_in[18];
  const float* aWhh0  = (const float*)d_in[19];
  const float* abih0  = (const float*)d_in[20];
  const float* abhh0  = (const float*)d_in[21];
  const float* aWih1  = (const float*)d_in[22];
  const float* aWhh1  = (const float*)d_in[23];
  const float* abih1  = (const float*)d_in[24];
  const float* abhh1  = (const float*)d_in[25];
  const float* att1W  = (const float*)d_in[26];
  const float* att1b  = (const float*)d_in[27];
  const float* att2W  = (const float*)d_in[28];
  const float* aloutW = (const float*)d_in[29];
  const float* aloutb = (const float*)d_in[30];

  float* out = (float*)d_out;  // [0:512) alstm_out, [512:1024) pred

  float* W = (float*)d_ws;
  float* h_enc = W; W += 10240 * 64;      // reused as r0 (steps 7-8)
  float* vbuf  = W; W += 256;
  float* s_src = W; W += 10240;
  float* s_dst = W; W += 10240;
  float* hout  = W; W += 10240 * 64;
  float* zbuf  = W; W += 512 * 20 * 64;
  float* r1    = W; W += 512 * 20 * 64;
  float* w3a0  = W; W += 24576;
  float* w3a1  = W; W += 24576;
  // time-disjoint aliases: encoder weight buffers live in the zbuf region
  // (consumed at step 2; zbuf written at step 6).
  float* w3e0 = zbuf;                  // [70][192]  = 13440 dw
  float* w3e1 = zbuf + 13440;          // [128][192] = 24576 dw (end 38016)

  static bool attr_done = false;
  if (!attr_done) {
    hipFuncSetAttribute((const void*)gru2_enc,
                        hipFuncAttributeMaxDynamicSharedMemorySize, E_LDS);
    hipFuncSetAttribute((const void*)gru1,
                        hipFuncAttributeMaxDynamicSharedMemorySize, A_LDS);
    attr_done = true;
  }

  // 1) weight prep (R1 j3-interleave format for all 4 GRU layers)
  w3_prep<<<32, 256, 0, stream>>>(Wih0, Whh0, Wih1, Whh1, aWih0, aWhh0,
                                  aWih1, aWhh1, w3e0, w3e1, w3a0, w3a1);
  // 2) fused 2-layer persistent GRU encoder: 256 blocks x 8 waves x SPW=5
  //    = 10240 seqs in ONE balanced round; register h-state + batched
  //    readlane groups (hazard-distance scheduling)
  gru2_enc<<<256, 512, E_LDS, stream>>>(x, w3e0, w3e1, bih0, bhh0, bih1,
                                        bhh1, h_enc);
  // 3) GAT score-vector prep
  gat_prep<<<1, 64, 0, stream>>>(transW, transb, a_vec, vbuf);
  // 4) per-row s_src/s_dst
  gat_svals<<<2560, 256, 0, stream>>>(h_enc, vbuf, s_src, s_dst);
  // 5) dense attention + residual
  gat_attn<<<2560, 256, 0, stream>>>(h_enc, s_src, s_dst, hout);
  // 6) fc + pred head + ALSTM input transform (z in [i][k][64])
  gat_out<<<2560, 256, 0, stream>>>(hout, fcW, fcb, fcoW, fcob, alinW, alinb,
                                    zbuf, out + 512);
  // 7) ALSTM GRU layer 0: z -> r0 (reuses h_enc storage)
  gru1<<<64, 512, A_LDS, stream>>>(zbuf, w3a0, abih0, abhh0, 20, h_enc);
  // 8) ALSTM GRU layer 1: r0 -> r1
  gru1<<<64, 512, A_LDS, stream>>>(h_enc, w3a1, abih1, abhh1, 20, r1);
  // 9) ALSTM attention head -> alstm_out
  alstm_head<<<128, 256, 0, stream>>>(r1, att1W, att1b, att2W, aloutW, aloutb,
                                      out);
}

// Round 13
// 1246.153 us; speedup vs baseline: 1.1405x; 1.1405x over previous
//
#include <hip/hip_runtime.h>

#define DEV __device__ __forceinline__

DEV float fast_rcp(float x) {
#if __has_builtin(__builtin_amdgcn_rcpf)
  return __builtin_amdgcn_rcpf(x);
#else
  return 1.0f / x;
#endif
}
DEV float sigm(float x) { return fast_rcp(1.0f + __expf(-x)); }
DEV float tanh_f(float x) {
  float e = __expf(-2.0f * fabsf(x));
  float t = 1.0f - 2.0f * e * fast_rcp(1.0f + e);
  return copysignf(t, x);
}
DEV float lrelu(float x) { return x > 0.0f ? x : 0.01f * x; }

DEV float wave_sum(float v) {
#pragma unroll
  for (int m = 32; m; m >>= 1) v += __shfl_xor(v, m);
  return v;
}
DEV float wave_max(float v) {
#pragma unroll
  for (int m = 32; m; m >>= 1) v = fmaxf(v, __shfl_xor(v, m));
  return v;
}
DEV float dot4(float4 w, float4 x, float acc) {
  acc = fmaf(w.x, x.x, acc);
  acc = fmaf(w.y, x.y, acc);
  acc = fmaf(w.z, x.z, acc);
  acc = fmaf(w.w, x.w, acc);
  return acc;
}

// SGPR broadcast (x-part only, 30/step — readlane is ~12cyc, fine at this count)
DEV float bcast(float v, int lane) {
  return __int_as_float(__builtin_amdgcn_readlane(__float_as_int(v), lane));
}

// DPP wave rotate-right by 1: lane n receives lane (n-1)&63's value.
// WAVE_ROR1 = 0x13C (gfx9-family DPP control; gfx950 is gfx9 lineage).
DEV float rot1(float v) {
  const int i = __float_as_int(v);
  return __int_as_float(
      __builtin_amdgcn_update_dpp(i, i, 0x13C, 0xF, 0xF, true));
}

// ---------------------------------------------------------------------------
// Persistent-GRU encoder, R15. Plateau diagnosis (R11-R14, 1086-1127us):
//  * LDS-broadcast h: DS return path replicates to 64 lanes (~2 B unique/cyc)
//    -> ~16k cyc/CU-step for h alone (R12/R13).
//  * readlane h: v_readlane has ~12 cyc intrinsic VALU occupancy (R14's
//    batching A/B proved it's throughput, not hazard) -> 11.9k of the 19k
//    busy cyc/wave-step (R10/R11/R14).
// R15 eliminates broadcast: SYSTOLIC DPP ROTATION. hrot[s] rotates across
// lanes via v_mov_b32 dpp wave_ror:1 (2-cyc VALU, no DS, no SGPR path);
// after r rotations lane j holds h[(j-r)&63]. Weights read along the
// diagonal row=(j-r)&63, col=j — bank (3j+g)%32 unchanged (192=6*32) ->
// still 2 lanes/bank, conflict-free (R10-measured ~0). Layer1's x-side
// (fresh h0) and h-side (h1_old) merge into ONE rotation loop.
// VALU/wave-step ~11k (was 19k); DS 576 b32/wave unchanged.
// Rules kept: rotation loops partially ROLLED (RULE 1); no min-waves
// launch-bounds (RULE 3). 256 blocks x 8 waves x SPW=5 = ONE balanced
// round. LDS = weights only (147,456 B). h/x state in registers.
// ---------------------------------------------------------------------------
constexpr int E_SPW = 5;
constexpr int E_WAVES = 8;
constexpr int L_W0 = 0;          // Whh0 rows (w3e0 rows 6..69): 64*192 dw
constexpr int L_W1 = 12288;      // w3e1: 128*192 dw
constexpr int E_DW = 36864;
constexpr int E_LDS = E_DW * 4;  // 147,456 B <= 160 KiB

__launch_bounds__(512)
__global__ void gru2_enc(const float* __restrict__ x,      // [10240][60][6]
                         const float* __restrict__ w3e0,   // [70][192] j3-interleave
                         const float* __restrict__ w3e1,   // [128][192]
                         const float* __restrict__ bih0, const float* __restrict__ bhh0,
                         const float* __restrict__ bih1, const float* __restrict__ bhh1,
                         float* __restrict__ h_out) {      // [10240][64]
  extern __shared__ float lds[];
  const int tid = threadIdx.x;
  const int wave = tid >> 6;
  const int j = tid & 63;
  const int j3 = j * 3;

  // cooperative weight load into LDS (coalesced float4)
  {
    const float4* s0 = (const float4*)(w3e0 + 6 * 192);  // Whh0 rows
    for (int i = tid; i < 12288 / 4; i += 512) ((float4*)(lds + L_W0))[i] = s0[i];
    const float4* s1 = (const float4*)w3e1;
    for (int i = tid; i < 24576 / 4; i += 512) ((float4*)(lds + L_W1))[i] = s1[i];
  }
  // register weights: Wih0 (6 rows x 3 gates per lane)
  float wx0[6][3];
#pragma unroll
  for (int k = 0; k < 6; ++k)
#pragma unroll
    for (int g = 0; g < 3; ++g) wx0[k][g] = w3e0[k * 192 + j3 + g];

  const float br0 = bih0[j] + bhh0[j];
  const float bz0 = bih0[64 + j] + bhh0[64 + j];
  const float bxn0 = bih0[128 + j];
  const float bhn0 = bhh0[128 + j];
  const float br1 = bih1[j] + bhh1[j];
  const float bz1 = bih1[64 + j] + bhh1[64 + j];
  const float bxn1 = bih1[128 + j];
  const float bhn1 = bhh1[128 + j];

  float h0r[E_SPW], h1r[E_SPW];
#pragma unroll
  for (int s = 0; s < E_SPW; ++s) { h0r[s] = 0.0f; h1r[s] = 0.0f; }
  __syncthreads();  // weights visible; the only barrier

  const int seq0 = blockIdx.x * (E_WAVES * E_SPW) + wave * E_SPW;
  // x carrier: lane j<30 holds component ci of seq si; consumed via readlane
  const int si = j / 6;
  const int ci = j - si * 6;
  const bool xlane = (j < 6 * E_SPW);
  const float* xg = x + (size_t)(seq0 + si) * 360 + ci;

  float xcur = xlane ? xg[0] : 0.0f;  // t = 0

  for (int t = 0; t < 60; ++t) {
    float xnext = (xlane && t + 1 < 60) ? xg[(size_t)(t + 1) * 6] : 0.0f;

    float ar[E_SPW], az[E_SPW], anx[E_SPW], anh[E_SPW];
#pragma unroll
    for (int s = 0; s < E_SPW; ++s) { ar[s] = 0.f; az[s] = 0.f; anx[s] = 0.f; anh[s] = 0.f; }

    // ---- layer0 h-part: systolic rotation over Whh0 (64 rows).
    // At rotation r, lane j holds h0_old[(j-r)&63] and multiplies weight
    // row (j-r)&63 (its own column j3) — diagonal access, bank-free.
    {
      float c0 = h0r[0], c1 = h0r[1], c2 = h0r[2], c3 = h0r[3], c4 = h0r[4];
      int krel = j;
#pragma clang loop unroll_count(4)
      for (int r = 0; r < 64; ++r) {
        const int wb = L_W0 + krel * 192 + j3;
        const float wr = lds[wb], wz = lds[wb + 1], wn = lds[wb + 2];
        ar[0] = fmaf(wr, c0, ar[0]); az[0] = fmaf(wz, c0, az[0]); anh[0] = fmaf(wn, c0, anh[0]);
        ar[1] = fmaf(wr, c1, ar[1]); az[1] = fmaf(wz, c1, az[1]); anh[1] = fmaf(wn, c1, anh[1]);
        ar[2] = fmaf(wr, c2, ar[2]); az[2] = fmaf(wz, c2, az[2]); anh[2] = fmaf(wn, c2, anh[2]);
        ar[3] = fmaf(wr, c3, ar[3]); az[3] = fmaf(wz, c3, az[3]); anh[3] = fmaf(wn, c3, anh[3]);
        ar[4] = fmaf(wr, c4, ar[4]); az[4] = fmaf(wz, c4, az[4]); anh[4] = fmaf(wn, c4, anh[4]);
        c0 = rot1(c0); c1 = rot1(c1); c2 = rot1(c2); c3 = rot1(c3); c4 = rot1(c4);
        krel = (krel - 1) & 63;
      }
    }

    // ---- layer0 x-part: register weights, x via readlane (only 30/step)
    {
      float xk_[E_SPW][6];
#pragma unroll
      for (int s = 0; s < E_SPW; ++s)
#pragma unroll
        for (int c = 0; c < 6; ++c) xk_[s][c] = bcast(xcur, s * 6 + c);
#pragma unroll
      for (int s = 0; s < E_SPW; ++s)
#pragma unroll
        for (int c = 0; c < 6; ++c) {
          ar[s] = fmaf(wx0[c][0], xk_[s][c], ar[s]);
          az[s] = fmaf(wx0[c][1], xk_[s][c], az[s]);
          anx[s] = fmaf(wx0[c][2], xk_[s][c], anx[s]);
        }
    }
    // ---- layer0 epilogue: lane j owns all 3 gates of unit j; pure register
#pragma unroll
    for (int s = 0; s < E_SPW; ++s) {
      float r = sigm(ar[s] + br0);
      float z = sigm(az[s] + bz0);
      float n = tanh_f(anx[s] + bxn0 + r * (anh[s] + bhn0));
      h0r[s] = (1.0f - z) * n + z * h0r[s];
    }

#pragma unroll
    for (int s = 0; s < E_SPW; ++s) { ar[s] = 0.f; az[s] = 0.f; anx[s] = 0.f; anh[s] = 0.f; }

    // ---- layer1, merged rotation: x-side over fresh h0 (W1 rows 0..63)
    //      and h-side over h1_old (W1 rows 64..127) share krel.
    {
      float a0 = h0r[0], a1 = h0r[1], a2 = h0r[2], a3 = h0r[3], a4 = h0r[4];
      float b0 = h1r[0], b1 = h1r[1], b2 = h1r[2], b3 = h1r[3], b4 = h1r[4];
      int krel = j;
#pragma clang loop unroll_count(2)
      for (int r = 0; r < 64; ++r) {
        const int wbx = L_W1 + krel * 192 + j3;
        const int wbh = wbx + 64 * 192;
        const float wrx = lds[wbx], wzx = lds[wbx + 1], wnx = lds[wbx + 2];
        const float wrh = lds[wbh], wzh = lds[wbh + 1], wnh = lds[wbh + 2];
        ar[0] = fmaf(wrx, a0, ar[0]); az[0] = fmaf(wzx, a0, az[0]); anx[0] = fmaf(wnx, a0, anx[0]);
        ar[1] = fmaf(wrx, a1, ar[1]); az[1] = fmaf(wzx, a1, az[1]); anx[1] = fmaf(wnx, a1, anx[1]);
        ar[2] = fmaf(wrx, a2, ar[2]); az[2] = fmaf(wzx, a2, az[2]); anx[2] = fmaf(wnx, a2, anx[2]);
        ar[3] = fmaf(wrx, a3, ar[3]); az[3] = fmaf(wzx, a3, az[3]); anx[3] = fmaf(wnx, a3, anx[3]);
        ar[4] = fmaf(wrx, a4, ar[4]); az[4] = fmaf(wzx, a4, az[4]); anx[4] = fmaf(wnx, a4, anx[4]);
        ar[0] = fmaf(wrh, b0, ar[0]); az[0] = fmaf(wzh, b0, az[0]); anh[0] = fmaf(wnh, b0, anh[0]);
        ar[1] = fmaf(wrh, b1, ar[1]); az[1] = fmaf(wzh, b1, az[1]); anh[1] = fmaf(wnh, b1, anh[1]);
        ar[2] = fmaf(wrh, b2, ar[2]); az[2] = fmaf(wzh, b2, az[2]); anh[2] = fmaf(wnh, b2, anh[2]);
        ar[3] = fmaf(wrh, b3, ar[3]); az[3] = fmaf(wzh, b3, az[3]); anh[3] = fmaf(wnh, b3, anh[3]);
        ar[4] = fmaf(wrh, b4, ar[4]); az[4] = fmaf(wzh, b4, az[4]); anh[4] = fmaf(wnh, b4, anh[4]);
        a0 = rot1(a0); a1 = rot1(a1); a2 = rot1(a2); a3 = rot1(a3); a4 = rot1(a4);
        b0 = rot1(b0); b1 = rot1(b1); b2 = rot1(b2); b3 = rot1(b3); b4 = rot1(b4);
        krel = (krel - 1) & 63;
      }
    }
    // ---- layer1 epilogue
#pragma unroll
    for (int s = 0; s < E_SPW; ++s) {
      float r = sigm(ar[s] + br1);
      float z = sigm(az[s] + bz1);
      float n = tanh_f(anx[s] + bxn1 + r * (anh[s] + bhn1));
      h1r[s] = (1.0f - z) * n + z * h1r[s];
    }
    xcur = xnext;
  }

#pragma unroll
  for (int s = 0; s < E_SPW; ++s)
    h_out[(size_t)(seq0 + s) * 64 + j] = h1r[s];
}

// ---------------------------------------------------------------------------
// Single-layer GRU for the ALSTM (I = 64). Unchanged (validated; small share
// of runtime). 8 waves/block, 1 seq/wave, grid 64.
// ---------------------------------------------------------------------------
constexpr int A_W_DW = 128 * 192;  // 24576
constexpr int A_WAVES = 8;
constexpr int A_LDS = (A_W_DW + A_WAVES * 128) * 4;  // 102400 B

__launch_bounds__(512, 2)
__global__ void gru1(const float* __restrict__ xin,  // [N][T][64]
                     const float* __restrict__ w3,   // [128][192]
                     const float* __restrict__ bih, const float* __restrict__ bhh,
                     int T,
                     float* __restrict__ rout) {     // [N][T][64]
  extern __shared__ float lds[];
  const int tid = threadIdx.x;
  const int wave = tid >> 6;
  const int j = tid & 63;
  const int j3 = j * 3;
  const int XB = A_W_DW + wave * 128;  // [0..63]=x_t, [64..127]=h

  {
    const float4* sp = (const float4*)w3;
    for (int i = tid; i < A_W_DW / 4; i += 512) ((float4*)lds)[i] = sp[i];
  }
  const float br = bih[j] + bhh[j];
  const float bz = bih[64 + j] + bhh[64 + j];
  const float bxn = bih[128 + j];
  const float bhn = bhh[128 + j];

  float hr = 0.0f;
  lds[XB + 64 + j] = 0.0f;
  __syncthreads();

  const int seq = blockIdx.x * A_WAVES + wave;
  const float* xs = xin + (size_t)seq * T * 64;

#define A_QUAD(WROW0, HOFF, AN)                                            \
  {                                                                        \
    float4 hv = *(const float4*)&lds[XB + (HOFF)];                         \
    _Pragma("unroll") for (int c = 0; c < 4; ++c) {                        \
      const float wr = lds[((WROW0) + c) * 192 + j3];                      \
      const float wz = lds[((WROW0) + c) * 192 + j3 + 1];                  \
      const float wn = lds[((WROW0) + c) * 192 + j3 + 2];                  \
      const float hc = (c == 0) ? hv.x : (c == 1) ? hv.y                   \
                      : (c == 2) ? hv.z : hv.w;                            \
      ar = fmaf(wr, hc, ar);                                               \
      az = fmaf(wz, hc, az);                                               \
      AN = fmaf(wn, hc, AN);                                               \
    }                                                                      \
  }

  float xcur = xs[j];  // t = 0
  for (int t = 0; t < T; ++t) {
    float xnext = (t + 1 < T) ? xs[(size_t)(t + 1) * 64 + j] : 0.0f;
    lds[XB + j] = xcur;  // wave-private; ordered by lgkmcnt

    float ar = 0.f, az = 0.f, anx = 0.f, anh = 0.f;
#pragma unroll
    for (int kq = 0; kq < 16; ++kq) A_QUAD(kq * 4, kq * 4, anx);        // input
#pragma unroll
    for (int kq = 0; kq < 16; ++kq) A_QUAD(64 + kq * 4, 64 + kq * 4, anh);  // rec

    float r = sigm(ar + br);
    float z = sigm(az + bz);
    float n = tanh_f(anx + bxn + r * (anh + bhn));
    float h = (1.0f - z) * n + z * hr;
    hr = h;
    lds[XB + 64 + j] = h;
    rout[((size_t)seq * T + t) * 64 + j] = h;
    xcur = xnext;
  }
#undef A_QUAD
}

// ---------------------------------------------------------------------------
// Weight interleave prep (R1 format): W3[k][j*3+g] =
//   (k<I ? Wih[g*64+j][k] : Whh[g*64+j][k-I])
// Sections: 0: e0 [70][192] (I=6); 1: e1 [128][192]; 2,3: ALSTM a0,a1.
// ---------------------------------------------------------------------------
__global__ void w3_prep(const float* __restrict__ Wih0, const float* __restrict__ Whh0,
                        const float* __restrict__ Wih1, const float* __restrict__ Whh1,
                        const float* __restrict__ aWih0, const float* __restrict__ aWhh0,
                        const float* __restrict__ aWih1, const float* __restrict__ aWhh1,
                        float* __restrict__ d_e0, float* __restrict__ d_e1,
                        float* __restrict__ d_a0, float* __restrict__ d_a1) {
  const int sec = blockIdx.x >> 3;
  const int bi = blockIdx.x & 7;
  const float* Wih; const float* Whh; float* dst; int I;
  if (sec == 0)      { Wih = Wih0;  Whh = Whh0;  dst = d_e0; I = 6; }
  else if (sec == 1) { Wih = Wih1;  Whh = Whh1;  dst = d_e1; I = 64; }
  else if (sec == 2) { Wih = aWih0; Whh = aWhh0; dst = d_a0; I = 64; }
  else               { Wih = aWih1; Whh = aWhh1; dst = d_a1; I = 64; }
  const int tot = (I + 64) * 192;
  for (int idx = bi * blockDim.x + threadIdx.x; idx < tot; idx += 8 * blockDim.x) {
    const int k = idx / 192;
    const int rem = idx - k * 192;
    const int jj = rem / 3;
    const int g = rem - jj * 3;
    dst[idx] = (k < I) ? Wih[(g * 64 + jj) * I + k] : Whh[(g * 64 + jj) * 64 + (k - I)];
  }
}

// ---------------------------------------------------------------------------
// GAT algebraic prep
// ---------------------------------------------------------------------------
__global__ void gat_prep(const float* __restrict__ tW, const float* __restrict__ tb,
                         const float* __restrict__ a, float* __restrict__ vbuf) {
  const int d = threadIdx.x;  // 64 threads
  float vd = 0.0f, vs = 0.0f;
  for (int e = 0; e < 64; ++e) {
    float w = tW[e * 64 + d];
    vd = fmaf(w, a[e], vd);
    vs = fmaf(w, a[64 + e], vs);
  }
  vbuf[d] = vd;
  vbuf[64 + d] = vs;
  if (d == 0) {
    float cd = 0.0f, cs = 0.0f;
    for (int e = 0; e < 64; ++e) {
      cd = fmaf(tb[e], a[e], cd);
      cs = fmaf(tb[e], a[64 + e], cs);
    }
    vbuf[128] = cd;
    vbuf[129] = cs;
  }
}

__global__ void gat_svals(const float* __restrict__ h_enc, const float* __restrict__ vbuf,
                          float* __restrict__ s_src, float* __restrict__ s_dst) {
  const int wave = (blockIdx.x * blockDim.x + threadIdx.x) >> 6;
  const int lane = threadIdx.x & 63;
  float h = h_enc[(size_t)wave * 64 + lane];
  float pd = h * vbuf[lane];
  float ps = h * vbuf[64 + lane];
  pd = wave_sum(pd);
  ps = wave_sum(ps);
  if (lane == 0) {
    s_dst[wave] = pd + vbuf[128];
    s_src[wave] = ps + vbuf[129];
  }
}

// ---------------------------------------------------------------------------
// Dense all-pairs attention per group k (m=512)
// ---------------------------------------------------------------------------
__launch_bounds__(256)
__global__ void gat_attn(const float* __restrict__ h_enc,
                         const float* __restrict__ s_src,
                         const float* __restrict__ s_dst,
                         float* __restrict__ hout) {
  const int k = blockIdx.x >> 7;
  const int tile = blockIdx.x & 127;
  const int wv = threadIdx.x >> 6;
  const int lane = threadIdx.x & 63;
  const int i = tile * 4 + wv;
  __shared__ float sdbuf[512];
  __shared__ __align__(16) float pbuf[4][512];

  for (int u = threadIdx.x; u < 512; u += 256) sdbuf[u] = s_dst[k * 512 + u];
  __syncthreads();

  const float si = s_src[k * 512 + i];
  float ev[8];
  float mx = -1e30f;
#pragma unroll
  for (int u = 0; u < 8; ++u) {
    ev[u] = lrelu(si + sdbuf[lane + u * 64]);
    mx = fmaxf(mx, ev[u]);
  }
  mx = wave_max(mx);
  float lsum = 0.0f;
#pragma unroll
  for (int u = 0; u < 8; ++u) {
    float p = __expf(ev[u] - mx);
    pbuf[wv][lane + u * 64] = p;
    lsum += p;
  }
  lsum = wave_sum(lsum);
  const float inv = fast_rcp(lsum);

  const float* hk = h_enc + (size_t)k * 512 * 64;
  const float4* pv = (const float4*)pbuf[wv];
  float acc0 = 0.0f, acc1 = 0.0f;
#pragma unroll 2
  for (int jj = 0; jj < 128; ++jj) {
    float4 p = pv[jj];
    const float* hp = hk + (size_t)(jj * 4) * 64 + lane;
    acc0 = fmaf(p.x, hp[0], acc0);
    acc1 = fmaf(p.y, hp[64], acc1);
    acc0 = fmaf(p.z, hp[128], acc0);
    acc1 = fmaf(p.w, hp[192], acc1);
  }
  hout[((size_t)k * 512 + i) * 64 + lane] =
      (acc0 + acc1) * inv + hk[(size_t)i * 64 + lane];
}

// ---------------------------------------------------------------------------
// Post-GAT transform + pred head + ALSTM input transform
// ---------------------------------------------------------------------------
__launch_bounds__(256)
__global__ void gat_out(const float* __restrict__ hin,
                        const float* __restrict__ fcW, const float* __restrict__ fcb,
                        const float* __restrict__ fcoW, const float* __restrict__ fcob,
                        const float* __restrict__ alinW, const float* __restrict__ alinb,
                        float* __restrict__ zout, float* __restrict__ pred) {
  const int wv = threadIdx.x >> 6;
  const int lane = threadIdx.x & 63;
  const int n = blockIdx.x * 4 + wv;  // [0,10240)
  const int k = n >> 9;
  const int i = n & 511;
  __shared__ __align__(16) float rbuf[4][64];
  __shared__ __align__(16) float rbuf2[4][64];

  float4 fw[16], aw[16];
  {
    const float4* p1 = (const float4*)(fcW + lane * 64);
    const float4* p2 = (const float4*)(alinW + lane * 64);
#pragma unroll
    for (int kk = 0; kk < 16; ++kk) fw[kk] = p1[kk];
#pragma unroll
    for (int kk = 0; kk < 16; ++kk) aw[kk] = p2[kk];
  }

  rbuf[wv][lane] = hin[(size_t)n * 64 + lane];
  float h2 = fcb[lane];
  const float4* rv = (const float4*)rbuf[wv];
#pragma unroll
  for (int kk = 0; kk < 16; ++kk) h2 = dot4(fw[kk], rv[kk], h2);

  if (k == 19) {
    float pv = lrelu(h2) * fcoW[lane];
    pv = wave_sum(pv);
    if (lane == 0) pred[i] = pv + fcob[0];
  }

  rbuf2[wv][lane] = h2;
  float zz = alinb[lane];
  const float4* rv2 = (const float4*)rbuf2[wv];
#pragma unroll
  for (int kk = 0; kk < 16; ++kk) zz = dot4(aw[kk], rv2[kk], zz);
  zout[((size_t)i * 20 + k) * 64 + lane] = tanh_f(zz);
}

// ---------------------------------------------------------------------------
// ALSTM attention head
// ---------------------------------------------------------------------------
__launch_bounds__(256)
__global__ void alstm_head(const float* __restrict__ r1,  // [512][20][64]
                           const float* __restrict__ W1,  // [32][64]
                           const float* __restrict__ b1,  // [32]
                           const float* __restrict__ W2,  // [32]
                           const float* __restrict__ Wo,  // [128]
                           const float* __restrict__ bo,  // [1]
                           float* __restrict__ alstm_out) {
  const int wv = threadIdx.x >> 6;
  const int lane = threadIdx.x & 63;
  const int i = blockIdx.x * 4 + wv;  // [0,512)
  const int e = lane & 31;
  __shared__ __align__(16) float rbuf[4][64];
  __shared__ float scb[4][20];

  float4 w1r[16];
  {
    const float4* p = (const float4*)(W1 + e * 64);
#pragma unroll
    for (int kk = 0; kk < 16; ++kk) w1r[kk] = p[kk];
  }
  const float b1e = b1[e];
  const float w2e = W2[e];

  for (int k = 0; k < 20; ++k) {
    rbuf[wv][lane] = r1[((size_t)i * 20 + k) * 64 + lane];
    float u = b1e;
    const float4* rp = (const float4*)rbuf[wv];
#pragma unroll
    for (int kk = 0; kk < 16; ++kk) u = dot4(w1r[kk], rp[kk], u);
    u = tanh_f(u) * w2e;
#pragma unroll
    for (int m = 16; m; m >>= 1) u += __shfl_xor(u, m);
    if (lane == 0) scb[wv][k] = u;
  }

  float mx = -1e30f;
#pragma unroll
  for (int k = 0; k < 20; ++k) mx = fmaxf(mx, scb[wv][k]);
  float p[20];
  float l = 0.0f;
#pragma unroll
  for (int k = 0; k < 20; ++k) {
    p[k] = __expf(scb[wv][k] - mx);
    l += p[k];
  }
  const float inv = fast_rcp(l);

  float oa = 0.0f, rlast = 0.0f;
#pragma unroll
  for (int k = 0; k < 20; ++k) {
    float rv = r1[((size_t)i * 20 + k) * 64 + lane];
    oa = fmaf(p[k], rv, oa);
    if (k == 19) rlast = rv;
  }
  oa *= inv;
  float v = fmaf(Wo[lane], rlast, Wo[64 + lane] * oa);
  v = wave_sum(v);
  if (lane == 0) alstm_out[i] = v + bo[0];
}

// ---------------------------------------------------------------------------
extern "C" void kernel_launch(void* const* d_in, const int* in_sizes, int n_in,
                              void* d_out, int out_size, void* d_ws, size_t ws_size,
                              hipStream_t stream) {
  const float* x      = (const float*)d_in[0];
  const float* Wih0   = (const float*)d_in[1];
  const float* Whh0   = (const float*)d_in[2];
  const float* bih0   = (const float*)d_in[3];
  const float* bhh0   = (const float*)d_in[4];
  const float* Wih1   = (const float*)d_in[5];
  const float* Whh1   = (const float*)d_in[6];
  const float* bih1   = (const float*)d_in[7];
  const float* bhh1   = (const float*)d_in[8];
  const float* transW = (const float*)d_in[9];
  const float* transb = (const float*)d_in[10];
  const float* a_vec  = (const float*)d_in[11];
  const float* fcW    = (const float*)d_in[12];
  const float* fcb    = (const float*)d_in[13];
  const float* fcoW   = (const float*)d_in[14];
  const float* fcob   = (const float*)d_in[15];
  const float* alinW  = (const float*)d_in[16];
  const float* alinb  = (const float*)d_in[17];
  const float* aWih0  = (const float*)d_in[18];
  const float* aWhh0  = (const float*)d_in[19];
  const float* abih0  = (const float*)d_in[20];
  const float* abhh0  = (const float*)d_in[21];
  const float* aWih1  = (const float*)d_in[22];
  const float* aWhh1  = (const float*)d_in[23];
  const float* abih1  = (const float*)d_in[24];
  const float* abhh1  = (const float*)d_in[25];
  const float* att1W  = (const float*)d_in[26];
  const float* att1b  = (const float*)d_in[27];
  const float* att2W  = (const float*)d_in[28];
  const float* aloutW = (const float*)d_in[29];
  const float* aloutb = (const float*)d_in[30];

  float* out = (float*)d_out;  // [0:512) alstm_out, [512:1024) pred

  float* W = (float*)d_ws;
  float* h_enc = W; W += 10240 * 64;      // reused as r0 (steps 7-8)
  float* vbuf  = W; W += 256;
  float* s_src = W; W += 10240;
  float* s_dst = W; W += 10240;
  float* hout  = W; W += 10240 * 64;
  float* zbuf  = W; W += 512 * 20 * 64;
  float* r1    = W; W += 512 * 20 * 64;
  float* w3a0  = W; W += 24576;
  float* w3a1  = W; W += 24576;
  // time-disjoint aliases: encoder weight buffers live in the zbuf region
  // (consumed at step 2; zbuf written at step 6).
  float* w3e0 = zbuf;                  // [70][192]  = 13440 dw
  float* w3e1 = zbuf + 13440;          // [128][192] = 24576 dw (end 38016)

  static bool attr_done = false;
  if (!attr_done) {
    hipFuncSetAttribute((const void*)gru2_enc,
                        hipFuncAttributeMaxDynamicSharedMemorySize, E_LDS);
    hipFuncSetAttribute((const void*)gru1,
                        hipFuncAttributeMaxDynamicSharedMemorySize, A_LDS);
    attr_done = true;
  }

  // 1) weight prep (R1 j3-interleave format for all 4 GRU layers)
  w3_prep<<<32, 256, 0, stream>>>(Wih0, Whh0, Wih1, Whh1, aWih0, aWhh0,
                                  aWih1, aWhh1, w3e0, w3e1, w3a0, w3a1);
  // 2) fused 2-layer persistent GRU encoder: 256 blocks x 8 waves x SPW=5
  //    = 10240 seqs in ONE balanced round; register h-state + DPP systolic
  //    rotation (zero broadcast cost)
  gru2_enc<<<256, 512, E_LDS, stream>>>(x, w3e0, w3e1, bih0, bhh0, bih1,
                                        bhh1, h_enc);
  // 3) GAT score-vector prep
  gat_prep<<<1, 64, 0, stream>>>(transW, transb, a_vec, vbuf);
  // 4) per-row s_src/s_dst
  gat_svals<<<2560, 256, 0, stream>>>(h_enc, vbuf, s_src, s_dst);
  // 5) dense attention + residual
  gat_attn<<<2560, 256, 0, stream>>>(h_enc, s_src, s_dst, hout);
  // 6) fc + pred head + ALSTM input transform (z in [i][k][64])
  gat_out<<<2560, 256, 0, stream>>>(hout, fcW, fcb, fcoW, fcob, alinW, alinb,
                                    zbuf, out + 512);
  // 7) ALSTM GRU layer 0: z -> r0 (reuses h_enc storage)
  gru1<<<64, 512, A_LDS, stream>>>(zbuf, w3a0, abih0, abhh0, 20, h_enc);
  // 8) ALSTM GRU layer 1: r0 -> r1
  gru1<<<64, 512, A_LDS, stream>>>(h_enc, w3a1, abih1, abhh1, 20, r1);
  // 9) ALSTM attention head -> alstm_out
  alstm_head<<<128, 256, 0, stream>>>(r1, att1W, att1b, att2W, aloutW, aloutb,
                                      out);
}

// Round 14
// 1227.118 us; speedup vs baseline: 1.1582x; 1.0155x over previous
//
#include <hip/hip_runtime.h>

#define DEV __device__ __forceinline__

DEV float fast_rcp(float x) {
#if __has_builtin(__builtin_amdgcn_rcpf)
  return __builtin_amdgcn_rcpf(x);
#else
  return 1.0f / x;
#endif
}
DEV float sigm(float x) { return fast_rcp(1.0f + __expf(-x)); }
DEV float tanh_f(float x) {
  float e = __expf(-2.0f * fabsf(x));
  float t = 1.0f - 2.0f * e * fast_rcp(1.0f + e);
  return copysignf(t, x);
}
DEV float lrelu(float x) { return x > 0.0f ? x : 0.01f * x; }

DEV float wave_sum(float v) {
#pragma unroll
  for (int m = 32; m; m >>= 1) v += __shfl_xor(v, m);
  return v;
}
DEV float wave_max(float v) {
#pragma unroll
  for (int m = 32; m; m >>= 1) v = fmaxf(v, __shfl_xor(v, m));
  return v;
}
DEV float dot4(float4 w, float4 x, float acc) {
  acc = fmaf(w.x, x.x, acc);
  acc = fmaf(w.y, x.y, acc);
  acc = fmaf(w.z, x.z, acc);
  acc = fmaf(w.w, x.w, acc);
  return acc;
}

// SGPR broadcast (x-part only, 30/step)
DEV float bcast(float v, int lane) {
  return __int_as_float(__builtin_amdgcn_readlane(__float_as_int(v), lane));
}

// DPP wave rotate-right by 1: lane n receives lane (n-1)&63's value.
DEV float rot1(float v) {
  const int i = __float_as_int(v);
  return __int_as_float(
      __builtin_amdgcn_update_dpp(i, i, 0x13C, 0xF, 0xF, true));
}

// ---------------------------------------------------------------------------
// Persistent-GRU encoder, R16. R15 (DPP systolic, 993us) verified; accounting
// now CLOSES with one metric correction: VALUBusy derived formula assumes
// SIMD-16 (gfx94x fallback) -> reports 2x true busy on gfx950's SIMD-32.
// True state: VALU ~17.6k cyc/SIMD-step, DS ~18.4k cyc/CU-step, measured
// 39.7k -> co-bound with ~55% overlap. Remaining identified waste: per-lane
// krel addressing (~600 VALU/wave-step: &63 wrap, x192, +j3, per-iter addr
// VGPRs blocking ds_read immediate folding).
// R16: PRE-SHIFTED DIAGONAL LAYOUT. Prep stores e3[d][j][g] =
// W[(g*64+j)*64 + ((j-d)&63)] so rotation d reads base + d*192 + j3:
// per-lane address computed ONCE (j3); d*768B folds into ds_read's 16-bit
// imm offset within each unroll-8 group (max 48384B, fits). Bank pattern
// (3j+g)%32 unchanged -> conflict-free (R10/R15-measured ~0). FMA/rot
// structure IDENTICAL to verified R15. unroll_count(8): 24 live weight
// regs, no spill risk (RULE 1 bans only FULL unroll). No min-waves
// launch-bounds (RULE 3). 256 blocks x 8 waves x SPW=5 = ONE round.
// LDS = weights only: 3 x 12288 dw = 147,456 B. h/x state in registers.
// ---------------------------------------------------------------------------
constexpr int E_SPW = 5;
constexpr int E_WAVES = 8;
constexpr int L_W0 = 0;          // e3h0 [64][192] shifted Whh0
constexpr int L_W1X = 12288;     // e3x1 [64][192] shifted Wih1
constexpr int L_W1H = 24576;     // e3h1 [64][192] shifted Whh1
constexpr int E_DW = 36864;
constexpr int E_LDS = E_DW * 4;  // 147,456 B <= 160 KiB

__launch_bounds__(512)
__global__ void gru2_enc(const float* __restrict__ x,      // [10240][60][6]
                         const float* __restrict__ w3e0,   // [70][192] (reg rows 0..5)
                         const float* __restrict__ e3h0,   // [64][192] shifted
                         const float* __restrict__ e3x1,   // [64][192] shifted
                         const float* __restrict__ e3h1,   // [64][192] shifted
                         const float* __restrict__ bih0, const float* __restrict__ bhh0,
                         const float* __restrict__ bih1, const float* __restrict__ bhh1,
                         float* __restrict__ h_out) {      // [10240][64]
  extern __shared__ float lds[];
  const int tid = threadIdx.x;
  const int wave = tid >> 6;
  const int j = tid & 63;
  const int j3 = j * 3;

  // cooperative weight load into LDS (coalesced float4)
  {
    const float4* s0 = (const float4*)e3h0;
    for (int i = tid; i < 12288 / 4; i += 512) ((float4*)(lds + L_W0))[i] = s0[i];
    const float4* s1 = (const float4*)e3x1;
    for (int i = tid; i < 12288 / 4; i += 512) ((float4*)(lds + L_W1X))[i] = s1[i];
    const float4* s2 = (const float4*)e3h1;
    for (int i = tid; i < 12288 / 4; i += 512) ((float4*)(lds + L_W1H))[i] = s2[i];
  }
  // register weights: Wih0 (6 rows x 3 gates per lane)
  float wx0[6][3];
#pragma unroll
  for (int k = 0; k < 6; ++k)
#pragma unroll
    for (int g = 0; g < 3; ++g) wx0[k][g] = w3e0[k * 192 + j3 + g];

  const float br0 = bih0[j] + bhh0[j];
  const float bz0 = bih0[64 + j] + bhh0[64 + j];
  const float bxn0 = bih0[128 + j];
  const float bhn0 = bhh0[128 + j];
  const float br1 = bih1[j] + bhh1[j];
  const float bz1 = bih1[64 + j] + bhh1[64 + j];
  const float bxn1 = bih1[128 + j];
  const float bhn1 = bhh1[128 + j];

  float h0r[E_SPW], h1r[E_SPW];
#pragma unroll
  for (int s = 0; s < E_SPW; ++s) { h0r[s] = 0.0f; h1r[s] = 0.0f; }
  __syncthreads();  // weights visible; the only barrier

  const int seq0 = blockIdx.x * (E_WAVES * E_SPW) + wave * E_SPW;
  // x carrier: lane j<30 holds component ci of seq si; consumed via readlane
  const int si = j / 6;
  const int ci = j - si * 6;
  const bool xlane = (j < 6 * E_SPW);
  const float* xg = x + (size_t)(seq0 + si) * 360 + ci;

  float xcur = xlane ? xg[0] : 0.0f;  // t = 0

  for (int t = 0; t < 60; ++t) {
    float xnext = (xlane && t + 1 < 60) ? xg[(size_t)(t + 1) * 6] : 0.0f;

    float ar[E_SPW], az[E_SPW], anx[E_SPW], anh[E_SPW];
#pragma unroll
    for (int s = 0; s < E_SPW; ++s) { ar[s] = 0.f; az[s] = 0.f; anx[s] = 0.f; anh[s] = 0.f; }

    // ---- layer0 h-part: systolic rotation over shifted Whh0.
    // At rotation d, lane j holds h0_old[(j-d)&63]; weight at d*192+j3 is
    // pre-shifted to match (prep: e3h0[d][j][g] = Whh0 col (j-d)&63).
    {
      float c0 = h0r[0], c1 = h0r[1], c2 = h0r[2], c3 = h0r[3], c4 = h0r[4];
#pragma clang loop unroll_count(8)
      for (int d = 0; d < 64; ++d) {
        const int wb = L_W0 + d * 192 + j3;
        const float wr = lds[wb], wz = lds[wb + 1], wn = lds[wb + 2];
        ar[0] = fmaf(wr, c0, ar[0]); az[0] = fmaf(wz, c0, az[0]); anh[0] = fmaf(wn, c0, anh[0]);
        ar[1] = fmaf(wr, c1, ar[1]); az[1] = fmaf(wz, c1, az[1]); anh[1] = fmaf(wn, c1, anh[1]);
        ar[2] = fmaf(wr, c2, ar[2]); az[2] = fmaf(wz, c2, az[2]); anh[2] = fmaf(wn, c2, anh[2]);
        ar[3] = fmaf(wr, c3, ar[3]); az[3] = fmaf(wz, c3, az[3]); anh[3] = fmaf(wn, c3, anh[3]);
        ar[4] = fmaf(wr, c4, ar[4]); az[4] = fmaf(wz, c4, az[4]); anh[4] = fmaf(wn, c4, anh[4]);
        c0 = rot1(c0); c1 = rot1(c1); c2 = rot1(c2); c3 = rot1(c3); c4 = rot1(c4);
      }
    }

    // ---- layer0 x-part: register weights, x via readlane (only 30/step)
    {
      float xk_[E_SPW][6];
#pragma unroll
      for (int s = 0; s < E_SPW; ++s)
#pragma unroll
        for (int c = 0; c < 6; ++c) xk_[s][c] = bcast(xcur, s * 6 + c);
#pragma unroll
      for (int s = 0; s < E_SPW; ++s)
#pragma unroll
        for (int c = 0; c < 6; ++c) {
          ar[s] = fmaf(wx0[c][0], xk_[s][c], ar[s]);
          az[s] = fmaf(wx0[c][1], xk_[s][c], az[s]);
          anx[s] = fmaf(wx0[c][2], xk_[s][c], anx[s]);
        }
    }
    // ---- layer0 epilogue: lane j owns all 3 gates of unit j; pure register
#pragma unroll
    for (int s = 0; s < E_SPW; ++s) {
      float r = sigm(ar[s] + br0);
      float z = sigm(az[s] + bz0);
      float n = tanh_f(anx[s] + bxn0 + r * (anh[s] + bhn0));
      h0r[s] = (1.0f - z) * n + z * h0r[s];
    }

#pragma unroll
    for (int s = 0; s < E_SPW; ++s) { ar[s] = 0.f; az[s] = 0.f; anx[s] = 0.f; anh[s] = 0.f; }

    // ---- layer1, merged rotation: x-side over fresh h0 and h-side over
    //      h1_old share the rotation index d.
    {
      float a0 = h0r[0], a1 = h0r[1], a2 = h0r[2], a3 = h0r[3], a4 = h0r[4];
      float b0 = h1r[0], b1 = h1r[1], b2 = h1r[2], b3 = h1r[3], b4 = h1r[4];
#pragma clang loop unroll_count(4)
      for (int d = 0; d < 64; ++d) {
        const int wbx = L_W1X + d * 192 + j3;
        const int wbh = L_W1H + d * 192 + j3;
        const float wrx = lds[wbx], wzx = lds[wbx + 1], wnx = lds[wbx + 2];
        const float wrh = lds[wbh], wzh = lds[wbh + 1], wnh = lds[wbh + 2];
        ar[0] = fmaf(wrx, a0, ar[0]); az[0] = fmaf(wzx, a0, az[0]); anx[0] = fmaf(wnx, a0, anx[0]);
        ar[1] = fmaf(wrx, a1, ar[1]); az[1] = fmaf(wzx, a1, az[1]); anx[1] = fmaf(wnx, a1, anx[1]);
        ar[2] = fmaf(wrx, a2, ar[2]); az[2] = fmaf(wzx, a2, az[2]); anx[2] = fmaf(wnx, a2, anx[2]);
        ar[3] = fmaf(wrx, a3, ar[3]); az[3] = fmaf(wzx, a3, az[3]); anx[3] = fmaf(wnx, a3, anx[3]);
        ar[4] = fmaf(wrx, a4, ar[4]); az[4] = fmaf(wzx, a4, az[4]); anx[4] = fmaf(wnx, a4, anx[4]);
        ar[0] = fmaf(wrh, b0, ar[0]); az[0] = fmaf(wzh, b0, az[0]); anh[0] = fmaf(wnh, b0, anh[0]);
        ar[1] = fmaf(wrh, b1, ar[1]); az[1] = fmaf(wzh, b1, az[1]); anh[1] = fmaf(wnh, b1, anh[1]);
        ar[2] = fmaf(wrh, b2, ar[2]); az[2] = fmaf(wzh, b2, az[2]); anh[2] = fmaf(wnh, b2, anh[2]);
        ar[3] = fmaf(wrh, b3, ar[3]); az[3] = fmaf(wzh, b3, az[3]); anh[3] = fmaf(wnh, b3, anh[3]);
        ar[4] = fmaf(wrh, b4, ar[4]); az[4] = fmaf(wzh, b4, az[4]); anh[4] = fmaf(wnh, b4, anh[4]);
        a0 = rot1(a0); a1 = rot1(a1); a2 = rot1(a2); a3 = rot1(a3); a4 = rot1(a4);
        b0 = rot1(b0); b1 = rot1(b1); b2 = rot1(b2); b3 = rot1(b3); b4 = rot1(b4);
      }
    }
    // ---- layer1 epilogue
#pragma unroll
    for (int s = 0; s < E_SPW; ++s) {
      float r = sigm(ar[s] + br1);
      float z = sigm(az[s] + bz1);
      float n = tanh_f(anx[s] + bxn1 + r * (anh[s] + bhn1));
      h1r[s] = (1.0f - z) * n + z * h1r[s];
    }
    xcur = xnext;
  }

#pragma unroll
  for (int s = 0; s < E_SPW; ++s)
    h_out[(size_t)(seq0 + s) * 64 + j] = h1r[s];
}

// ---------------------------------------------------------------------------
// Single-layer GRU for the ALSTM (I = 64). Unchanged (validated; small share
// of runtime). 8 waves/block, 1 seq/wave, grid 64.
// ---------------------------------------------------------------------------
constexpr int A_W_DW = 128 * 192;  // 24576
constexpr int A_WAVES = 8;
constexpr int A_LDS = (A_W_DW + A_WAVES * 128) * 4;  // 102400 B

__launch_bounds__(512, 2)
__global__ void gru1(const float* __restrict__ xin,  // [N][T][64]
                     const float* __restrict__ w3,   // [128][192]
                     const float* __restrict__ bih, const float* __restrict__ bhh,
                     int T,
                     float* __restrict__ rout) {     // [N][T][64]
  extern __shared__ float lds[];
  const int tid = threadIdx.x;
  const int wave = tid >> 6;
  const int j = tid & 63;
  const int j3 = j * 3;
  const int XB = A_W_DW + wave * 128;  // [0..63]=x_t, [64..127]=h

  {
    const float4* sp = (const float4*)w3;
    for (int i = tid; i < A_W_DW / 4; i += 512) ((float4*)lds)[i] = sp[i];
  }
  const float br = bih[j] + bhh[j];
  const float bz = bih[64 + j] + bhh[64 + j];
  const float bxn = bih[128 + j];
  const float bhn = bhh[128 + j];

  float hr = 0.0f;
  lds[XB + 64 + j] = 0.0f;
  __syncthreads();

  const int seq = blockIdx.x * A_WAVES + wave;
  const float* xs = xin + (size_t)seq * T * 64;

#define A_QUAD(WROW0, HOFF, AN)                                            \
  {                                                                        \
    float4 hv = *(const float4*)&lds[XB + (HOFF)];                         \
    _Pragma("unroll") for (int c = 0; c < 4; ++c) {                        \
      const float wr = lds[((WROW0) + c) * 192 + j3];                      \
      const float wz = lds[((WROW0) + c) * 192 + j3 + 1];                  \
      const float wn = lds[((WROW0) + c) * 192 + j3 + 2];                  \
      const float hc = (c == 0) ? hv.x : (c == 1) ? hv.y                   \
                      : (c == 2) ? hv.z : hv.w;                            \
      ar = fmaf(wr, hc, ar);                                               \
      az = fmaf(wz, hc, az);                                               \
      AN = fmaf(wn, hc, AN);                                               \
    }                                                                      \
  }

  float xcur = xs[j];  // t = 0
  for (int t = 0; t < T; ++t) {
    float xnext = (t + 1 < T) ? xs[(size_t)(t + 1) * 64 + j] : 0.0f;
    lds[XB + j] = xcur;  // wave-private; ordered by lgkmcnt

    float ar = 0.f, az = 0.f, anx = 0.f, anh = 0.f;
#pragma unroll
    for (int kq = 0; kq < 16; ++kq) A_QUAD(kq * 4, kq * 4, anx);        // input
#pragma unroll
    for (int kq = 0; kq < 16; ++kq) A_QUAD(64 + kq * 4, 64 + kq * 4, anh);  // rec

    float r = sigm(ar + br);
    float z = sigm(az + bz);
    float n = tanh_f(anx + bxn + r * (anh + bhn));
    float h = (1.0f - z) * n + z * hr;
    hr = h;
    lds[XB + 64 + j] = h;
    rout[((size_t)seq * T + t) * 64 + j] = h;
    xcur = xnext;
  }
#undef A_QUAD
}

// ---------------------------------------------------------------------------
// Weight prep. Sections (8 blocks each):
//  0: w3e0 [70][192] j3-interleave (register rows; I=6)
//  1: e3h0 [64][192] shifted-diagonal <- Whh0
//  2: e3x1 [64][192] shifted-diagonal <- Wih1
//  3: e3h1 [64][192] shifted-diagonal <- Whh1
//  4: a0   [128][192] j3-interleave (ALSTM L0)
//  5: a1   [128][192] j3-interleave (ALSTM L1)
// shifted-diagonal: dst[d*192 + j*3 + g] = W[(g*64+j)*64 + ((j-d)&63)]
// ---------------------------------------------------------------------------
__global__ void w3_prep(const float* __restrict__ Wih0, const float* __restrict__ Whh0,
                        const float* __restrict__ Wih1, const float* __restrict__ Whh1,
                        const float* __restrict__ aWih0, const float* __restrict__ aWhh0,
                        const float* __restrict__ aWih1, const float* __restrict__ aWhh1,
                        float* __restrict__ d_e0, float* __restrict__ d_h0,
                        float* __restrict__ d_x1, float* __restrict__ d_h1,
                        float* __restrict__ d_a0, float* __restrict__ d_a1) {
  const int sec = blockIdx.x >> 3;
  const int bi = blockIdx.x & 7;

  if (sec == 0) {  // j3 format, encoder L0 (I=6): [70][192]
    for (int idx = bi * blockDim.x + threadIdx.x; idx < 70 * 192; idx += 8 * blockDim.x) {
      const int k = idx / 192;
      const int rem = idx - k * 192;
      const int jj = rem / 3;
      const int g = rem - jj * 3;
      d_e0[idx] = (k < 6) ? Wih0[(g * 64 + jj) * 6 + k]
                          : Whh0[(g * 64 + jj) * 64 + (k - 6)];
    }
  } else if (sec <= 3) {  // shifted-diagonal sections
    const float* src = (sec == 1) ? Whh0 : (sec == 2) ? Wih1 : Whh1;
    float* dst = (sec == 1) ? d_h0 : (sec == 2) ? d_x1 : d_h1;
    for (int idx = bi * blockDim.x + threadIdx.x; idx < 64 * 192; idx += 8 * blockDim.x) {
      const int d = idx / 192;
      const int rem = idx - d * 192;
      const int jj = rem / 3;
      const int g = rem - jj * 3;
      dst[idx] = src[(g * 64 + jj) * 64 + ((jj - d) & 63)];
    }
  } else {  // ALSTM j3 format: [128][192]
    const float* Wih = (sec == 4) ? aWih0 : aWih1;
    const float* Whh = (sec == 4) ? aWhh0 : aWhh1;
    float* dst = (sec == 4) ? d_a0 : d_a1;
    for (int idx = bi * blockDim.x + threadIdx.x; idx < 128 * 192; idx += 8 * blockDim.x) {
      const int k = idx / 192;
      const int rem = idx - k * 192;
      const int jj = rem / 3;
      const int g = rem - jj * 3;
      dst[idx] = (k < 64) ? Wih[(g * 64 + jj) * 64 + k] : Whh[(g * 64 + jj) * 64 + (k - 64)];
    }
  }
}

// ---------------------------------------------------------------------------
// GAT algebraic prep
// ---------------------------------------------------------------------------
__global__ void gat_prep(const float* __restrict__ tW, const float* __restrict__ tb,
                         const float* __restrict__ a, float* __restrict__ vbuf) {
  const int d = threadIdx.x;  // 64 threads
  float vd = 0.0f, vs = 0.0f;
  for (int e = 0; e < 64; ++e) {
    float w = tW[e * 64 + d];
    vd = fmaf(w, a[e], vd);
    vs = fmaf(w, a[64 + e], vs);
  }
  vbuf[d] = vd;
  vbuf[64 + d] = vs;
  if (d == 0) {
    float cd = 0.0f, cs = 0.0f;
    for (int e = 0; e < 64; ++e) {
      cd = fmaf(tb[e], a[e], cd);
      cs = fmaf(tb[e], a[64 + e], cs);
    }
    vbuf[128] = cd;
    vbuf[129] = cs;
  }
}

__global__ void gat_svals(const float* __restrict__ h_enc, const float* __restrict__ vbuf,
                          float* __restrict__ s_src, float* __restrict__ s_dst) {
  const int wave = (blockIdx.x * blockDim.x + threadIdx.x) >> 6;
  const int lane = threadIdx.x & 63;
  float h = h_enc[(size_t)wave * 64 + lane];
  float pd = h * vbuf[lane];
  float ps = h * vbuf[64 + lane];
  pd = wave_sum(pd);
  ps = wave_sum(ps);
  if (lane == 0) {
    s_dst[wave] = pd + vbuf[128];
    s_src[wave] = ps + vbuf[129];
  }
}

// ---------------------------------------------------------------------------
// Dense all-pairs attention per group k (m=512)
// ---------------------------------------------------------------------------
__launch_bounds__(256)
__global__ void gat_attn(const float* __restrict__ h_enc,
                         const float* __restrict__ s_src,
                         const float* __restrict__ s_dst,
                         float* __restrict__ hout) {
  const int k = blockIdx.x >> 7;
  const int tile = blockIdx.x & 127;
  const int wv = threadIdx.x >> 6;
  const int lane = threadIdx.x & 63;
  const int i = tile * 4 + wv;
  __shared__ float sdbuf[512];
  __shared__ __align__(16) float pbuf[4][512];

  for (int u = threadIdx.x; u < 512; u += 256) sdbuf[u] = s_dst[k * 512 + u];
  __syncthreads();

  const float si = s_src[k * 512 + i];
  float ev[8];
  float mx = -1e30f;
#pragma unroll
  for (int u = 0; u < 8; ++u) {
    ev[u] = lrelu(si + sdbuf[lane + u * 64]);
    mx = fmaxf(mx, ev[u]);
  }
  mx = wave_max(mx);
  float lsum = 0.0f;
#pragma unroll
  for (int u = 0; u < 8; ++u) {
    float p = __expf(ev[u] - mx);
    pbuf[wv][lane + u * 64] = p;
    lsum += p;
  }
  lsum = wave_sum(lsum);
  const float inv = fast_rcp(lsum);

  const float* hk = h_enc + (size_t)k * 512 * 64;
  const float4* pv = (const float4*)pbuf[wv];
  float acc0 = 0.0f, acc1 = 0.0f;
#pragma unroll 2
  for (int jj = 0; jj < 128; ++jj) {
    float4 p = pv[jj];
    const float* hp = hk + (size_t)(jj * 4) * 64 + lane;
    acc0 = fmaf(p.x, hp[0], acc0);
    acc1 = fmaf(p.y, hp[64], acc1);
    acc0 = fmaf(p.z, hp[128], acc0);
    acc1 = fmaf(p.w, hp[192], acc1);
  }
  hout[((size_t)k * 512 + i) * 64 + lane] =
      (acc0 + acc1) * inv + hk[(size_t)i * 64 + lane];
}

// ---------------------------------------------------------------------------
// Post-GAT transform + pred head + ALSTM input transform
// ---------------------------------------------------------------------------
__launch_bounds__(256)
__global__ void gat_out(const float* __restrict__ hin,
                        const float* __restrict__ fcW, const float* __restrict__ fcb,
                        const float* __restrict__ fcoW, const float* __restrict__ fcob,
                        const float* __restrict__ alinW, const float* __restrict__ alinb,
                        float* __restrict__ zout, float* __restrict__ pred) {
  const int wv = threadIdx.x >> 6;
  const int lane = threadIdx.x & 63;
  const int n = blockIdx.x * 4 + wv;  // [0,10240)
  const int k = n >> 9;
  const int i = n & 511;
  __shared__ __align__(16) float rbuf[4][64];
  __shared__ __align__(16) float rbuf2[4][64];

  float4 fw[16], aw[16];
  {
    const float4* p1 = (const float4*)(fcW + lane * 64);
    const float4* p2 = (const float4*)(alinW + lane * 64);
#pragma unroll
    for (int kk = 0; kk < 16; ++kk) fw[kk] = p1[kk];
#pragma unroll
    for (int kk = 0; kk < 16; ++kk) aw[kk] = p2[kk];
  }

  rbuf[wv][lane] = hin[(size_t)n * 64 + lane];
  float h2 = fcb[lane];
  const float4* rv = (const float4*)rbuf[wv];
#pragma unroll
  for (int kk = 0; kk < 16; ++kk) h2 = dot4(fw[kk], rv[kk], h2);

  if (k == 19) {
    float pv = lrelu(h2) * fcoW[lane];
    pv = wave_sum(pv);
    if (lane == 0) pred[i] = pv + fcob[0];
  }

  rbuf2[wv][lane] = h2;
  float zz = alinb[lane];
  const float4* rv2 = (const float4*)rbuf2[wv];
#pragma unroll
  for (int kk = 0; kk < 16; ++kk) zz = dot4(aw[kk], rv2[kk], zz);
  zout[((size_t)i * 20 + k) * 64 + lane] = tanh_f(zz);
}

// ---------------------------------------------------------------------------
// ALSTM attention head
// ---------------------------------------------------------------------------
__launch_bounds__(256)
__global__ void alstm_head(const float* __restrict__ r1,  // [512][20][64]
                           const float* __restrict__ W1,  // [32][64]
                           const float* __restrict__ b1,  // [32]
                           const float* __restrict__ W2,  // [32]
                           const float* __restrict__ Wo,  // [128]
                           const float* __restrict__ bo,  // [1]
                           float* __restrict__ alstm_out) {
  const int wv = threadIdx.x >> 6;
  const int lane = threadIdx.x & 63;
  const int i = blockIdx.x * 4 + wv;  // [0,512)
  const int e = lane & 31;
  __shared__ __align__(16) float rbuf[4][64];
  __shared__ float scb[4][20];

  float4 w1r[16];
  {
    const float4* p = (const float4*)(W1 + e * 64);
#pragma unroll
    for (int kk = 0; kk < 16; ++kk) w1r[kk] = p[kk];
  }
  const float b1e = b1[e];
  const float w2e = W2[e];

  for (int k = 0; k < 20; ++k) {
    rbuf[wv][lane] = r1[((size_t)i * 20 + k) * 64 + lane];
    float u = b1e;
    const float4* rp = (const float4*)rbuf[wv];
#pragma unroll
    for (int kk = 0; kk < 16; ++kk) u = dot4(w1r[kk], rp[kk], u);
    u = tanh_f(u) * w2e;
#pragma unroll
    for (int m = 16; m; m >>= 1) u += __shfl_xor(u, m);
    if (lane == 0) scb[wv][k] = u;
  }

  float mx = -1e30f;
#pragma unroll
  for (int k = 0; k < 20; ++k) mx = fmaxf(mx, scb[wv][k]);
  float p[20];
  float l = 0.0f;
#pragma unroll
  for (int k = 0; k < 20; ++k) {
    p[k] = __expf(scb[wv][k] - mx);
    l += p[k];
  }
  const float inv = fast_rcp(l);

  float oa = 0.0f, rlast = 0.0f;
#pragma unroll
  for (int k = 0; k < 20; ++k) {
    float rv = r1[((size_t)i * 20 + k) * 64 + lane];
    oa = fmaf(p[k], rv, oa);
    if (k == 19) rlast = rv;
  }
  oa *= inv;
  float v = fmaf(Wo[lane], rlast, Wo[64 + lane] * oa);
  v = wave_sum(v);
  if (lane == 0) alstm_out[i] = v + bo[0];
}

// ---------------------------------------------------------------------------
extern "C" void kernel_launch(void* const* d_in, const int* in_sizes, int n_in,
                              void* d_out, int out_size, void* d_ws, size_t ws_size,
                              hipStream_t stream) {
  const float* x      = (const float*)d_in[0];
  const float* Wih0   = (const float*)d_in[1];
  const float* Whh0   = (const float*)d_in[2];
  const float* bih0   = (const float*)d_in[3];
  const float* bhh0   = (const float*)d_in[4];
  const float* Wih1   = (const float*)d_in[5];
  const float* Whh1   = (const float*)d_in[6];
  const float* bih1   = (const float*)d_in[7];
  const float* bhh1   = (const float*)d_in[8];
  const float* transW = (const float*)d_in[9];
  const float* transb = (const float*)d_in[10];
  const float* a_vec  = (const float*)d_in[11];
  const float* fcW    = (const float*)d_in[12];
  const float* fcb    = (const float*)d_in[13];
  const float* fcoW   = (const float*)d_in[14];
  const float* fcob   = (const float*)d_in[15];
  const float* alinW  = (const float*)d_in[16];
  const float* alinb  = (const float*)d_in[17];
  const float* aWih0  = (const float*)d_in[18];
  const float* aWhh0  = (const float*)d_in[19];
  const float* abih0  = (const float*)d_in[20];
  const float* abhh0  = (const float*)d_in[21];
  const float* aWih1  = (const float*)d_in[22];
  const float* aWhh1  = (const float*)d_in[23];
  const float* abih1  = (const float*)d_in[24];
  const float* abhh1  = (const float*)d_in[25];
  const float* att1W  = (const float*)d_in[26];
  const float* att1b  = (const float*)d_in[27];
  const float* att2W  = (const float*)d_in[28];
  const float* aloutW = (const float*)d_in[29];
  const float* aloutb = (const float*)d_in[30];

  float* out = (float*)d_out;  // [0:512) alstm_out, [512:1024) pred

  float* W = (float*)d_ws;
  float* h_enc = W; W += 10240 * 64;      // reused as r0 (steps 7-8)
  float* vbuf  = W; W += 256;
  float* s_src = W; W += 10240;
  float* s_dst = W; W += 10240;
  float* hout  = W; W += 10240 * 64;
  float* zbuf  = W; W += 512 * 20 * 64;
  float* r1    = W; W += 512 * 20 * 64;
  float* w3a0  = W; W += 24576;
  float* w3a1  = W; W += 24576;
  // time-disjoint aliases: encoder weight buffers live in the zbuf region
  // (consumed at step 2; zbuf written at step 6).
  float* w3e0 = zbuf;                  // [70][192] = 13440 dw
  float* e3h0 = zbuf + 13440;          // [64][192] = 12288 dw
  float* e3x1 = zbuf + 25728;          // [64][192] = 12288 dw
  float* e3h1 = zbuf + 38016;          // [64][192] = 12288 dw (end 50304)

  static bool attr_done = false;
  if (!attr_done) {
    hipFuncSetAttribute((const void*)gru2_enc,
                        hipFuncAttributeMaxDynamicSharedMemorySize, E_LDS);
    hipFuncSetAttribute((const void*)gru1,
                        hipFuncAttributeMaxDynamicSharedMemorySize, A_LDS);
    attr_done = true;
  }

  // 1) weight prep (shifted-diagonal for systolic encoder + ALSTM j3)
  w3_prep<<<48, 256, 0, stream>>>(Wih0, Whh0, Wih1, Whh1, aWih0, aWhh0,
                                  aWih1, aWhh1, w3e0, e3h0, e3x1, e3h1,
                                  w3a0, w3a1);
  // 2) fused 2-layer persistent GRU encoder: 256 blocks x 8 waves x SPW=5
  //    = 10240 seqs in ONE balanced round; DPP systolic + pre-shifted
  //    weights (uniform base + immediate offsets)
  gru2_enc<<<256, 512, E_LDS, stream>>>(x, w3e0, e3h0, e3x1, e3h1,
                                        bih0, bhh0, bih1, bhh1, h_enc);
  // 3) GAT score-vector prep
  gat_prep<<<1, 64, 0, stream>>>(transW, transb, a_vec, vbuf);
  // 4) per-row s_src/s_dst
  gat_svals<<<2560, 256, 0, stream>>>(h_enc, vbuf, s_src, s_dst);
  // 5) dense attention + residual
  gat_attn<<<2560, 256, 0, stream>>>(h_enc, s_src, s_dst, hout);
  // 6) fc + pred head + ALSTM input transform (z in [i][k][64])
  gat_out<<<2560, 256, 0, stream>>>(hout, fcW, fcb, fcoW, fcob, alinW, alinb,
                                    zbuf, out + 512);
  // 7) ALSTM GRU layer 0: z -> r0 (reuses h_enc storage)
  gru1<<<64, 512, A_LDS, stream>>>(zbuf, w3a0, abih0, abhh0, 20, h_enc);
  // 8) ALSTM GRU layer 1: r0 -> r1
  gru1<<<64, 512, A_LDS, stream>>>(h_enc, w3a1, abih1, abhh1, 20, r1);
  // 9) ALSTM attention head -> alstm_out
  alstm_head<<<128, 256, 0, stream>>>(r1, att1W, att1b, att2W, aloutW, aloutb,
                                      out);
}